// Round 4
// baseline (293.408 us; speedup 1.0000x reference)
//
#include <hip/hip_runtime.h>
#include <hip/hip_bf16.h>
#include <math.h>

#define BB 32
#define SS 2048
#define HE 1024
#define HD 1024
#define WROW (HE + HD)   // 2048

typedef __attribute__((ext_vector_type(8))) short bf16x8;
typedef __attribute__((ext_vector_type(4))) float f32x4;
typedef __attribute__((ext_vector_type(8))) unsigned short u16x8;

__device__ __forceinline__ unsigned short f2bf(float f) {
    union { float f; unsigned u; } v; v.f = f;
    unsigned r = v.u + 0x7fffu + ((v.u >> 16) & 1u);   // RNE
    return (unsigned short)(r >> 16);
}

__device__ __forceinline__ unsigned int pk2(float x, float y) {
    union { __hip_bfloat162 h; unsigned int u; } c;
    c.h = __float22bfloat162_rn(float2{x, y});          // v_cvt_pk_bf16_f32
    return c.u;
}

#define LGKM0()  asm volatile("s_waitcnt lgkmcnt(0)" ::: "memory")
#define BAR()    asm volatile("s_barrier" ::: "memory")

// ---------------- cvt: W_enc fp32 -> bf16 fragment-major ----------------
// Record (g, ksg): 64 lanes x 16B; lane l = W[d=g*16+(l&15)][k=ksg*32+(l>>4)*8 ..+8]
// g = d>>4 (0..63), ksg = k>>5 (0..31). One wave's bg load = 1KB contiguous.
__global__ __launch_bounds__(256) void k_cvt_wfrag(const float* __restrict__ W,
                                                   unsigned short* __restrict__ wf) {
    int i = blockIdx.x * 256 + threadIdx.x;   // 0..131071 (8-elem chunks)
    int d = i >> 7;                            // 0..1023
    int c = i & 127;                           // k-chunk: k = c*8
    const float4* src = (const float4*)(W + (size_t)d * WROW + c * 8);
    float4 a = src[0], b2 = src[1];
    u16x8 o;
    o[0] = f2bf(a.x);  o[1] = f2bf(a.y);  o[2] = f2bf(a.z);  o[3] = f2bf(a.w);
    o[4] = f2bf(b2.x); o[5] = f2bf(b2.y); o[6] = f2bf(b2.z); o[7] = f2bf(b2.w);
    int ksg = c >> 2, hi = c & 3;
    int l   = (d & 15) + 16 * hi;
    int g   = d >> 4;
    *(u16x8*)(wf + ((size_t)(g * 32 + ksg) * 64 + l) * 8) = o;
}

// ---------------- proj_dec: W_dec read ONCE total ----------------
__global__ __launch_bounds__(256) void k_projdec2(const float* __restrict__ dec,
                                                  const float* __restrict__ W,
                                                  float* __restrict__ proj) {
    const int tid = threadIdx.x;
    const int dl = tid >> 6;
    const int b  = (tid >> 1) & 31;
    const int hf = tid & 1;
    const int d  = blockIdx.x * 4 + dl;
    const float* wrow = W + (size_t)d * WROW + HE + hf * 512;
    const float* dv   = dec + b * HD + hf * 512;
    float s = 0.f;
    #pragma unroll 4
    for (int e = 0; e < 512; e += 4) {
        float4 w4 = *(const float4*)(wrow + e);
        float4 x4 = *(const float4*)(dv + e);
        s += w4.x * x4.x + w4.y * x4.y + w4.z * x4.z + w4.w * x4.w;
    }
    s += __shfl_xor(s, 1, 64);
    if (hf == 0) proj[b * HD + d] = s;
}

// ---------------- 4-wave 128x128 MFMA scores; 3 blocks/CU ----------------
// R4: occupancy attack. Wave-tile 64x64 (acc[4][4]=64 AGPR), 4 waves (2Mx2N),
// block tile 128 tokens x 128 d, K-step 64. Reg budget ~160/wave ->
// __launch_bounds__(256,3) -> 3 blocks/CU = 12 waves = 3/SIMD, three
// INDEPENDENT barrier domains (R3's independence + actual extra wave slots).
// M=128 halves B-bytes/MFMA vs R2 (B-L2 traffic ~1GB). A redundancy 8x
// logical; enc (256MB) is L3-resident and nb-blocks of a token-tile are
// XCD-adjacent -> L2/L3 absorb (R0 evidence: 4x redundancy, FETCH still 164MB).
// A: reg-staged fp32->bf16 in TWO K-halves (areg[4] reused) -> XOR-swizzled
//    LDS dbuf [2][128x64] bf16 = 32KB.
// B: fragment-major global->reg (L2-resident wf), consume-then-reload 1 tile
//    ahead; compiler emits counted vmcnt. Single lgkm0+barrier per K-tile.
__global__ __launch_bounds__(256, 3) void k_scores_mfma8b(
        const float* __restrict__ enc,             // [65536][1024] fp32
        const unsigned short* __restrict__ wf,     // fragment-major bf16 W_enc
        const float* __restrict__ V,
        const float* __restrict__ proj,            // [32][1024]
        float* __restrict__ psc) {                 // [8][65536] partial scores
    __shared__ unsigned short SM[16384];           // 32 KB: A dbuf [2][8192]

    const int tid = threadIdx.x;
    const int wv = tid >> 6, ln = tid & 63, l15 = ln & 15, lg = ln >> 4;
    const int wr = wv >> 1, wc = wv & 1;

    // T1: bijective XCD swizzle over 4096 blocks; the 8 nb-slices of one
    // token-tile run adjacently on one XCD -> A re-reads hit that XCD's L2.
    const int lid  = (blockIdx.x & 7) * 512 + (blockIdx.x >> 3);
    const int trow = lid >> 3, nb = lid & 7;
    const int t0   = trow * 128;
    const int b    = t0 >> 11;
    const int g0   = nb * 8 + wc * 4;              // wf d-group base for this wave

    f32x4 acc[4][4];
    #pragma unroll
    for (int m = 0; m < 4; m++)
        #pragma unroll
        for (int n = 0; n < 4; n++) acc[m][n] = (f32x4){0.f, 0.f, 0.f, 0.f};

    float4 areg[4];            // HALF a K-tile of A: 128 rows x 32 k, 16 fp32/thread
    bf16x8 bg0[4], bg1[4];     // B frags ks0 / ks1 (consume-then-reload)

    // thread -> (row, kseg): row = tid>>1 (0..127), kseg = tid&1 (16 fp32 each)
    #define LOAD_A(kabs) do { \
        const float4* g_ = (const float4*)(enc + (size_t)(t0 + (tid >> 1)) * 1024 + (kabs) + (tid & 1) * 16); \
        areg[0] = g_[0]; areg[1] = g_[1]; areg[2] = g_[2]; areg[3] = g_[3]; \
    } while (0)

    // two u16x8 stores: chunks c0 = h*4 + (tid&1)*2 and c0+1, XOR-swizzled/row
    #define CVTW_A(buf, h) do { \
        int row_ = tid >> 1; \
        int c0_  = (h) * 4 + (tid & 1) * 2; \
        union { u16x8 s; uint4 u; } pk_; \
        pk_.u.x = pk2(areg[0].x, areg[0].y); \
        pk_.u.y = pk2(areg[0].z, areg[0].w); \
        pk_.u.z = pk2(areg[1].x, areg[1].y); \
        pk_.u.w = pk2(areg[1].z, areg[1].w); \
        *(u16x8*)&SM[(buf) * 8192 + row_ * 64 + ((c0_ ^ (row_ & 7)) << 3)] = pk_.s; \
        pk_.u.x = pk2(areg[2].x, areg[2].y); \
        pk_.u.y = pk2(areg[2].z, areg[2].w); \
        pk_.u.z = pk2(areg[3].x, areg[3].y); \
        pk_.u.w = pk2(areg[3].z, areg[3].w); \
        *(u16x8*)&SM[(buf) * 8192 + row_ * 64 + (((c0_ + 1) ^ (row_ & 7)) << 3)] = pk_.s; \
    } while (0)

    // bg fragment load: g = g0 + n, record (g*32 + t*2 + ksl), lane ln
    #define LOADB(bgx, tt, ksl) do { \
        _Pragma("unroll") \
        for (int n = 0; n < 4; n++) { \
            int g_ = g0 + n; \
            bgx[n] = *(const bf16x8*)(wf + ((size_t)(g_ * 32 + (tt) * 2 + (ksl)) * 64 + ln) * 8); \
        } } while (0)

    #define RD_A(af, Ac, ks) do { \
        _Pragma("unroll") \
        for (int m = 0; m < 4; m++) { \
            int row_ = wr * 64 + m * 16 + l15; \
            af[m] = *(const bf16x8*)&(Ac)[row_ * 64 + ((((ks) + lg) ^ (row_ & 7)) << 3)]; \
        } } while (0)

    #define MFMA16(bg, af) do { \
        __builtin_amdgcn_s_setprio(1); \
        _Pragma("unroll") \
        for (int m = 0; m < 4; m++) \
            _Pragma("unroll") \
            for (int n = 0; n < 4; n++) \
                acc[m][n] = __builtin_amdgcn_mfma_f32_16x16x32_bf16(af[m], bg[n], acc[m][n], 0, 0, 0); \
        __builtin_amdgcn_s_setprio(0); } while (0)

    // ---- prologue: bg(0) both halves; A(0) staged (2 halves); A(1,h0) in flight ----
    LOADB(bg0, 0, 0); LOADB(bg1, 0, 1);
    LOAD_A(0);
    CVTW_A(0, 0);
    LOAD_A(32);
    CVTW_A(0, 1);
    LOAD_A(64);                // A(1,h0)
    LGKM0(); BAR();

    for (int t = 0; t < 16; ++t) {
        const int cur = t & 1, nxt = cur ^ 1;
        const unsigned short* Ac = SM + cur * 8192;
        bf16x8 af[4];

        // ks0
        RD_A(af, Ac, 0);
        MFMA16(bg0, af);

        // slot A: bg0 dead -> reload for t+1; convert A(t+1,h0); issue A(t+1,h1)
        if (t < 15) {
            LOADB(bg0, t + 1, 0);
            CVTW_A(nxt, 0);                     // counted vmcnt on areg only
            LOAD_A((t + 1) * 64 + 32);          // A(t+1,h1)
        }

        // ks1
        RD_A(af, Ac, 4);
        MFMA16(bg1, af);

        // slot B: bg1 dead -> reload; convert A(t+1,h1); issue A(t+2,h0)
        if (t < 15) {
            LOADB(bg1, t + 1, 1);
            CVTW_A(nxt, 1);
            if (t < 14) LOAD_A((t + 2) * 64);
            LGKM0(); BAR();                     // A dbuf coherence; B stays in flight
        }
    }
    #undef LOAD_A
    #undef CVTW_A
    #undef LOADB
    #undef RD_A
    #undef MFMA16

    // ---- fused epilogue: sc[m][j] = sum_n V[d]*tanh(acc + proj) ----
    float sc[4][4];
    #pragma unroll
    for (int m = 0; m < 4; m++)
        #pragma unroll
        for (int j = 0; j < 4; j++) sc[m][j] = 0.f;
    #pragma unroll
    for (int n = 0; n < 4; n++) {
        int d = nb * 128 + wc * 64 + n * 16 + l15;
        float pd  = proj[b * 1024 + d];
        float vv  = V[d];
        float vv2 = 2.f * vv;
        #pragma unroll
        for (int m = 0; m < 4; m++)
            #pragma unroll
            for (int j = 0; j < 4; j++) {
                float y  = acc[m][n][j] + pd;
                float e2 = __expf(2.f * y);                 // saturates at +/-inf
                float r  = __builtin_amdgcn_rcpf(e2 + 1.f);
                sc[m][j] += vv - vv2 * r;                   // vv * tanh(y)
            }
    }

    __syncthreads();           // all waves done with LDS; safe to alias
    float* red = (float*)SM;   // 128 tokens x 32 cols, rotated = 16KB
    #pragma unroll
    for (int m = 0; m < 4; m++)
        #pragma unroll
        for (int j = 0; j < 4; j++) {
            int tok = wr * 64 + m * 16 + lg * 4 + j;
            int col = wc * 16 + l15;
            red[tok * 32 + ((col + tok) & 31)] = sc[m][j];
        }
    __syncthreads();
    if (tid < 128) {
        float s = 0.f;
        #pragma unroll
        for (int x = 0; x < 32; x++) s += red[tid * 32 + ((x + tid) & 31)];
        psc[nb * 65536 + t0 + tid] = s;
    }
}

// ---------------- masked softmax over S (sums 8 nb-slice partials) ----------------
__global__ __launch_bounds__(256) void k_softmax_p(const float* __restrict__ psc,
                                                   const int* __restrict__ mask,
                                                   float* __restrict__ attn) {
    __shared__ float sred[256];
    const int b = blockIdx.x, tid = threadIdx.x;
    float vals[8];
    int   msk[8];
    float lmax = -1e30f;
    #pragma unroll
    for (int i = 0; i < 8; i++) {
        int s = tid + i * 256;
        float v = 0.f;
        #pragma unroll
        for (int z = 0; z < 8; z++) v += psc[z * 65536 + b * SS + s];
        vals[i] = v;
        msk[i]  = mask[b * SS + s];
        if (!msk[i]) lmax = fmaxf(lmax, vals[i]);
    }
    sred[tid] = lmax; __syncthreads();
    for (int off = 128; off > 0; off >>= 1) {
        if (tid < off) sred[tid] = fmaxf(sred[tid], sred[tid + off]);
        __syncthreads();
    }
    float m = sred[0];
    __syncthreads();
    float ex[8];
    float lsum = 0.f;
    #pragma unroll
    for (int i = 0; i < 8; i++) {
        ex[i] = msk[i] ? 0.f : __expf(vals[i] - m);
        lsum += ex[i];
    }
    sred[tid] = lsum; __syncthreads();
    for (int off = 128; off > 0; off >>= 1) {
        if (tid < off) sred[tid] += sred[tid + off];
        __syncthreads();
    }
    float inv = 1.f / sred[0];
    #pragma unroll
    for (int i = 0; i < 8; i++) attn[b * SS + tid + i * 256] = ex[i] * inv;
}

// ---------------- ctx partials over s-chunks, masked-skip (no atomics) ----------
__global__ __launch_bounds__(256) void k_ctx_part(const float* __restrict__ enc,
                                                  const float* __restrict__ attn,
                                                  float* __restrict__ pctx) {
    const int b = blockIdx.x, z = blockIdx.y, tid = threadIdx.x;   // z: 0..15, 128 rows each
    float4 acc = {0.f, 0.f, 0.f, 0.f};
    const float4* e4 = (const float4*)(enc + ((size_t)b * SS + z * 128) * HE);
    const float*  ar = attn + b * SS + z * 128;
    for (int s = 0; s < 128; s++) {
        float a = ar[s];
        if (a != 0.f) {   // masked tokens have exactly-zero attn -> skip row read
            float4 v = e4[(size_t)s * 256 + tid];
            acc.x += a * v.x; acc.y += a * v.y; acc.z += a * v.z; acc.w += a * v.w;
        }
    }
    *(float4*)(pctx + ((size_t)z * 32 + b) * 1024 + tid * 4) = acc;
}

__global__ __launch_bounds__(256) void k_ctx_red(const float* __restrict__ pctx,
                                                 float* __restrict__ ctx) {
    int i = blockIdx.x * 256 + threadIdx.x;   // 0..32767
    float s = 0.f;
    #pragma unroll
    for (int z = 0; z < 16; z++) s += pctx[z * 32768 + i];
    ctx[i] = s;
}

// ================= fp32 fallback (round-0 proven path) =================
__global__ __launch_bounds__(256) void k_scores_f32(const float* __restrict__ enc,
                                                    const float* __restrict__ W,
                                                    const float* __restrict__ V,
                                                    const float* __restrict__ proj,
                                                    float* __restrict__ scores) {
    __shared__ float As[64][20];
    __shared__ float Bs[64][20];
    __shared__ float red[64][17];
    const int t0 = blockIdx.x * 64;
    const int b  = t0 >> 11;
    const int tid = threadIdx.x;
    const int tx = tid & 15, ty = tid >> 4;
    const int lrow = tid >> 2, lc4 = (tid & 3) * 4;
    float sc[4] = {0.f, 0.f, 0.f, 0.f};
    for (int n0 = 0; n0 < HD; n0 += 64) {
        float C[4][4] = {};
        for (int k0 = 0; k0 < HE; k0 += 16) {
            *(float4*)&As[lrow][lc4] = *(const float4*)(enc + (size_t)(t0 + lrow) * HE + k0 + lc4);
            *(float4*)&Bs[lrow][lc4] = *(const float4*)(W + (size_t)(n0 + lrow) * WROW + k0 + lc4);
            __syncthreads();
            #pragma unroll
            for (int k4 = 0; k4 < 16; k4 += 4) {
                float4 a[4], bb[4];
                #pragma unroll
                for (int i = 0; i < 4; i++) a[i]  = *(float4*)&As[ty * 4 + i][k4];
                #pragma unroll
                for (int j = 0; j < 4; j++) bb[j] = *(float4*)&Bs[tx * 4 + j][k4];
                #pragma unroll
                for (int i = 0; i < 4; i++)
                    #pragma unroll
                    for (int j = 0; j < 4; j++)
                        C[i][j] += a[i].x * bb[j].x + a[i].y * bb[j].y +
                                   a[i].z * bb[j].z + a[i].w * bb[j].w;
            }
            __syncthreads();
        }
        #pragma unroll
        for (int j = 0; j < 4; j++) {
            int d = n0 + tx * 4 + j;
            float pd = proj[b * HD + d];
            float v  = V[d];
            #pragma unroll
            for (int i = 0; i < 4; i++) {
                float y  = C[i][j] + pd;
                float e2 = __expf(2.f * y);
                sc[i] += v * (1.f - 2.f / (e2 + 1.f));
            }
        }
    }
    #pragma unroll
    for (int i = 0; i < 4; i++) red[ty * 4 + i][tx] = sc[i];
    __syncthreads();
    if (tid < 64) {
        float s = 0.f;
        #pragma unroll
        for (int x = 0; x < 16; x++) s += red[tid][x];
        scores[t0 + tid] = s;
    }
}

__global__ __launch_bounds__(256) void k_softmax_f32(float* __restrict__ sc_attn,
                                                     const int* __restrict__ mask) {
    __shared__ float sred[256];
    const int b = blockIdx.x, tid = threadIdx.x;
    float vals[8]; int msk[8];
    float lmax = -1e30f;
    #pragma unroll
    for (int i = 0; i < 8; i++) {
        int s = tid + i * 256;
        vals[i] = sc_attn[b * SS + s];
        msk[i]  = mask[b * SS + s];
        if (!msk[i]) lmax = fmaxf(lmax, vals[i]);
    }
    sred[tid] = lmax; __syncthreads();
    for (int off = 128; off > 0; off >>= 1) {
        if (tid < off) sred[tid] = fmaxf(sred[tid], sred[tid + off]);
        __syncthreads();
    }
    float m = sred[0];
    __syncthreads();
    float ex[8]; float lsum = 0.f;
    #pragma unroll
    for (int i = 0; i < 8; i++) { ex[i] = msk[i] ? 0.f : __expf(vals[i] - m); lsum += ex[i]; }
    sred[tid] = lsum; __syncthreads();
    for (int off = 128; off > 0; off >>= 1) {
        if (tid < off) sred[tid] += sred[tid + off];
        __syncthreads();
    }
    float inv = 1.f / sred[0];
    #pragma unroll
    for (int i = 0; i < 8; i++) sc_attn[b * SS + tid + i * 256] = ex[i] * inv;
}

__global__ __launch_bounds__(256) void k_ctx_atomic(const float* __restrict__ enc,
                                                    const float* __restrict__ attn,
                                                    float* __restrict__ ctx) {
    const int b = blockIdx.x;
    const int e = blockIdx.y * 256 + threadIdx.x;
    const int s0 = blockIdx.z * 256;
    float sum = 0.f;
    for (int s = s0; s < s0 + 256; s++)
        sum += attn[b * SS + s] * enc[((size_t)b * SS + s) * HE + e];
    atomicAdd(&ctx[b * HE + e], sum);
}

extern "C" void kernel_launch(void* const* d_in, const int* in_sizes, int n_in,
                              void* d_out, int out_size, void* d_ws, size_t ws_size,
                              hipStream_t stream) {
    const float* enc  = (const float*)d_in[0];
    const float* dec  = (const float*)d_in[1];
    const int*   mask = (const int*)d_in[2];
    const float* W    = (const float*)d_in[3];
    const float* V    = (const float*)d_in[4];

    float* out  = (float*)d_out;
    float* ctx  = out;               // [32][1024]
    float* attn = out + BB * HE;     // [32][2048]

    // ws layout (bytes): wf 2 MiB | proj 128 KiB | psc 2 MiB | pctx 2 MiB
    const size_t WF_OFF = 0, PROJ_OFF = 2097152, PSC_OFF = PROJ_OFF + 131072,
                 PCTX_OFF = PSC_OFF + 2097152, WS_NEED = PCTX_OFF + 2097152;
    if (ws_size >= WS_NEED) {
        char* w = (char*)d_ws;
        unsigned short* wf = (unsigned short*)(w + WF_OFF);
        float* proj        = (float*)(w + PROJ_OFF);
        float* psc         = (float*)(w + PSC_OFF);
        float* pctx        = (float*)(w + PCTX_OFF);

        k_cvt_wfrag<<<512, 256, 0, stream>>>(W, wf);
        k_projdec2<<<256, 256, 0, stream>>>(dec, W, proj);
        k_scores_mfma8b<<<4096, 256, 0, stream>>>(enc, wf, V, proj, psc);
        k_softmax_p<<<BB, 256, 0, stream>>>(psc, mask, attn);
        k_ctx_part<<<dim3(BB, 16), 256, 0, stream>>>(enc, attn, pctx);
        k_ctx_red<<<128, 256, 0, stream>>>(pctx, ctx);
    } else {
        float* proj  = ctx;
        float* score = attn;
        k_projdec2<<<256, 256, 0, stream>>>(dec, W, proj);
        k_scores_f32<<<(BB * SS) / 64, 256, 0, stream>>>(enc, W, V, proj, score);
        k_softmax_f32<<<BB, 256, 0, stream>>>(score, mask);
        hipMemsetAsync(ctx, 0, (size_t)BB * HE * sizeof(float), stream);
        k_ctx_atomic<<<dim3(BB, HE / 256, 8), 256, 0, stream>>>(enc, attn, ctx);
    }
}

// Round 5
// 221.774 us; speedup vs baseline: 1.3230x; 1.3230x over previous
//
#include <hip/hip_runtime.h>
#include <hip/hip_bf16.h>
#include <math.h>

#define BB 32
#define SS 2048
#define HE 1024
#define HD 1024
#define WROW (HE + HD)   // 2048

typedef __attribute__((ext_vector_type(8))) short bf16x8;
typedef __attribute__((ext_vector_type(4))) float f32x4;
typedef __attribute__((ext_vector_type(16))) float f32x16;
typedef __attribute__((ext_vector_type(8))) unsigned short u16x8;

__device__ __forceinline__ unsigned short f2bf(float f) {
    union { float f; unsigned u; } v; v.f = f;
    unsigned r = v.u + 0x7fffu + ((v.u >> 16) & 1u);   // RNE
    return (unsigned short)(r >> 16);
}

__device__ __forceinline__ unsigned int pk2(float x, float y) {
    union { __hip_bfloat162 h; unsigned int u; } c;
    c.h = __float22bfloat162_rn(float2{x, y});          // v_cvt_pk_bf16_f32
    return c.u;
}

#define LGKM0()  asm volatile("s_waitcnt lgkmcnt(0)" ::: "memory")
#define BAR()    asm volatile("s_barrier" ::: "memory")

// ---------------- cvt: W_enc fp32 -> bf16 fragment-major (32x32x16 records) ----
// Record (g, ks): 64 lanes x 16B; lane l = W[d=g*32+(l&31)][k=ks*16+(l>>5)*8 ..+8]
// g = d>>5 (0..31), ks = k>>4 (0..63). Matches B-operand of mfma_32x32x16_bf16.
__global__ __launch_bounds__(256) void k_cvt_wfrag(const float* __restrict__ W,
                                                   unsigned short* __restrict__ wf) {
    int i = blockIdx.x * 256 + threadIdx.x;   // 0..131071 (8-elem chunks)
    int d = i >> 7;                            // 0..1023
    int c = i & 127;                           // k-chunk: k = c*8
    const float4* src = (const float4*)(W + (size_t)d * WROW + c * 8);
    float4 a = src[0], b2 = src[1];
    u16x8 o;
    o[0] = f2bf(a.x);  o[1] = f2bf(a.y);  o[2] = f2bf(a.z);  o[3] = f2bf(a.w);
    o[4] = f2bf(b2.x); o[5] = f2bf(b2.y); o[6] = f2bf(b2.z); o[7] = f2bf(b2.w);
    int ks = c >> 1;                           // k>>4
    int l  = (d & 31) + 32 * (c & 1);          // (l>>5) = k-half
    int g  = d >> 5;
    *(u16x8*)(wf + ((size_t)(g * 64 + ks) * 64 + l) * 8) = o;
}

// ---------------- proj_dec: W_dec read ONCE total ----------------
__global__ __launch_bounds__(256) void k_projdec2(const float* __restrict__ dec,
                                                  const float* __restrict__ W,
                                                  float* __restrict__ proj) {
    const int tid = threadIdx.x;
    const int dl = tid >> 6;
    const int b  = (tid >> 1) & 31;
    const int hf = tid & 1;
    const int d  = blockIdx.x * 4 + dl;
    const float* wrow = W + (size_t)d * WROW + HE + hf * 512;
    const float* dv   = dec + b * HD + hf * 512;
    float s = 0.f;
    #pragma unroll 4
    for (int e = 0; e < 512; e += 4) {
        float4 w4 = *(const float4*)(wrow + e);
        float4 x4 = *(const float4*)(dv + e);
        s += w4.x * x4.x + w4.y * x4.y + w4.z * x4.z + w4.w * x4.w;
    }
    s += __shfl_xor(s, 1, 64);
    if (hf == 0) proj[b * HD + d] = s;
}

// ---------------- 8-wave 64x1024 scores, 32x32x16 MFMA ----------------
// R5: R2's proven geometry (64 tokens x full d=1024, A staged ONCE, 8 waves
// each 64x128, single lgkm0+barrier per K-tile) with the MFMA shape swapped
// 16x16x32 -> 32x32x16: half the MFMA instructions (32/wave/tile), 1015 vs
// 844 FLOP/cyc pipe rate, each LDS A-fragment feeds 4 long MFMAs.
// acc[2][4] f32x16 = 128 AGPR. A: reg-staged fp32->bf16 -> XOR-swizzled LDS
// dbuf [2][64x64] = 16 KB. B: fragment-major global->reg (L2-resident wf),
// consume-then-reload half-tile (8 frags = 32 VGPR live) one tile ahead.
// Fragment maps (gfx950): A row=l&31,k=(l>>5)*8..+8; B col=l&31,k=(l>>5)*8..;
// C col=l&31, row=(r&3)+8*(r>>2)+4*(l>>5)  [m74/m101 verified].
__global__ __launch_bounds__(512, 2) void k_scores_mfma8b(
        const float* __restrict__ enc,             // [65536][1024] fp32
        const unsigned short* __restrict__ wf,     // fragment-major bf16 W_enc
        const float* __restrict__ V,
        const float* __restrict__ proj,            // [32][1024]
        float* __restrict__ psc) {                 // [65536] final scores
    __shared__ unsigned short SM[8192];            // 16 KB: A dbuf [2][4096]

    const int tid = threadIdx.x;
    const int wv = tid >> 6, ln = tid & 63, l31 = ln & 31, hi = ln >> 5;

    // T1: bijective XCD swizzle over 1024 blocks
    const int lid  = (blockIdx.x & 7) * 128 + (blockIdx.x >> 3);
    const int t0   = lid * 64;
    const int b    = t0 >> 11;

    f32x16 acc[2][4];
    #pragma unroll
    for (int m = 0; m < 2; m++)
        #pragma unroll
        for (int n = 0; n < 4; n++)
            #pragma unroll
            for (int r = 0; r < 16; r++) acc[m][n][r] = 0.f;

    float4 areg[2];            // one K-tile of A: 64 rows x 64 k fp32, 8 fp32/thread
    bf16x8 bgE[8], bgF[8];     // B frags: [kk*4+n], E = ks 0,1  F = ks 2,3

    #define LOAD_A(k) do { \
        const float4* g_ = (const float4*)(enc + (size_t)(t0 + (tid >> 3)) * 1024 + (k) + (tid & 7) * 8); \
        areg[0] = g_[0]; areg[1] = g_[1]; \
    } while (0)

    #define CVTW_A(buf) do { \
        int row_ = tid >> 3; \
        union { u16x8 s; uint4 u; } pk_; \
        pk_.u.x = pk2(areg[0].x, areg[0].y); \
        pk_.u.y = pk2(areg[0].z, areg[0].w); \
        pk_.u.z = pk2(areg[1].x, areg[1].y); \
        pk_.u.w = pk2(areg[1].z, areg[1].w); \
        *(u16x8*)&SM[(buf) * 4096 + row_ * 64 + (((tid & 7) ^ (row_ & 7)) << 3)] = pk_.s; \
    } while (0)

    // B record: (g = wv*4 + n)*64 + t*4 + ksabs, lane ln
    #define LOADB(bgx, tt, ksb) do { \
        _Pragma("unroll") \
        for (int kk = 0; kk < 2; kk++) \
            _Pragma("unroll") \
            for (int n = 0; n < 4; n++) \
                bgx[kk * 4 + n] = *(const bf16x8*)(wf + ((size_t)((wv * 4 + n) * 64 + (tt) * 4 + (ksb) + kk) * 64 + ln) * 8); \
        } while (0)

    // one half-K-step (2 ks) of the wave-tile: 4 ds_reads + 16 MFMA
    #define HALF(bg, ksb, Ac) do { \
        _Pragma("unroll") \
        for (int kk = 0; kk < 2; kk++) { \
            bf16x8 af0, af1; \
            { int c_ = ((ksb) + kk) * 2 + hi; int row_ = l31; \
              af0 = *(const bf16x8*)&(Ac)[row_ * 64 + ((c_ ^ (row_ & 7)) << 3)]; } \
            { int c_ = ((ksb) + kk) * 2 + hi; int row_ = 32 + l31; \
              af1 = *(const bf16x8*)&(Ac)[row_ * 64 + ((c_ ^ (row_ & 7)) << 3)]; } \
            __builtin_amdgcn_s_setprio(1); \
            _Pragma("unroll") \
            for (int n = 0; n < 4; n++) \
                acc[0][n] = __builtin_amdgcn_mfma_f32_32x32x16_bf16(af0, bg[kk * 4 + n], acc[0][n], 0, 0, 0); \
            _Pragma("unroll") \
            for (int n = 0; n < 4; n++) \
                acc[1][n] = __builtin_amdgcn_mfma_f32_32x32x16_bf16(af1, bg[kk * 4 + n], acc[1][n], 0, 0, 0); \
            __builtin_amdgcn_s_setprio(0); \
        } } while (0)

    // ---- prologue: bg(0) both halves, A(0)->LDS, A(1) in flight ----
    LOADB(bgE, 0, 0); LOADB(bgF, 0, 2);
    LOAD_A(0);
    CVTW_A(0);                 // compiler waits A(0) loads, leaves bg in flight
    LOAD_A(64);                // A(1)
    LGKM0(); BAR();

    for (int t = 0; t < 16; ++t) {
        const int cur = t & 1, nxt = cur ^ 1;
        const unsigned short* Ac = SM + cur * 4096;

        // ks 0,1
        HALF(bgE, 0, Ac);

        // slot: bgE dead -> reload for t+1; convert A(t+1)->LDS nxt; issue A(t+2)
        if (t < 15) {
            LOADB(bgE, t + 1, 0);
            CVTW_A(nxt);                       // counted vmcnt on areg only
            if (t < 14) LOAD_A((t + 2) * 64);
        }

        // ks 2,3
        HALF(bgF, 2, Ac);

        if (t < 15) {
            LOADB(bgF, t + 1, 2);
            LGKM0(); BAR();                    // A dbuf coherence; B stays in flight
        }
    }
    #undef LOAD_A
    #undef CVTW_A
    #undef LOADB
    #undef HALF

    // ---- fused epilogue: sc[m][r] = sum_n V[d]*tanh(acc + proj) ----
    float sc[2][16];
    #pragma unroll
    for (int m = 0; m < 2; m++)
        #pragma unroll
        for (int r = 0; r < 16; r++) sc[m][r] = 0.f;
    #pragma unroll
    for (int n = 0; n < 4; n++) {
        int d = wv * 128 + n * 32 + l31;
        float pd  = proj[b * 1024 + d];
        float vv  = V[d];
        float vv2 = 2.f * vv;
        #pragma unroll
        for (int m = 0; m < 2; m++)
            #pragma unroll
            for (int r = 0; r < 16; r++) {
                float y  = acc[m][n][r] + pd;
                float e2 = __expf(2.f * y);                 // saturates at +/-inf
                float rc = __builtin_amdgcn_rcpf(e2 + 1.f);
                sc[m][r] += vv - vv2 * rc;                  // vv * tanh(y)
            }
    }

    // butterfly sum over the 32-lane column group (halves independent)
    #pragma unroll
    for (int m = 0; m < 2; m++)
        #pragma unroll
        for (int r = 0; r < 16; r++) {
            float v = sc[m][r];
            v += __shfl_xor(v, 1, 64);
            v += __shfl_xor(v, 2, 64);
            v += __shfl_xor(v, 4, 64);
            v += __shfl_xor(v, 8, 64);
            v += __shfl_xor(v, 16, 64);
            sc[m][r] = v;
        }

    __syncthreads();           // all waves done with LDS; safe to alias
    float* redf = (float*)SM;  // [64 tokens][8 waves] f32 = 2KB
    if (l31 == 0) {
        #pragma unroll
        for (int m = 0; m < 2; m++)
            #pragma unroll
            for (int r = 0; r < 16; r++) {
                int tok = m * 32 + (r & 3) + 8 * (r >> 2) + 4 * hi;
                redf[tok * 8 + wv] = sc[m][r];
            }
    }
    __syncthreads();
    if (tid < 64) {
        float s = 0.f;
        #pragma unroll
        for (int w = 0; w < 8; w++) s += redf[tid * 8 + w];
        psc[t0 + tid] = s;
    }
}

// ---------------- masked softmax over S (final scores input) ----------------
__global__ __launch_bounds__(256) void k_softmax_p(const float* __restrict__ psc,
                                                   const int* __restrict__ mask,
                                                   float* __restrict__ attn) {
    __shared__ float sred[256];
    const int b = blockIdx.x, tid = threadIdx.x;
    float vals[8];
    int   msk[8];
    float lmax = -1e30f;
    #pragma unroll
    for (int i = 0; i < 8; i++) {
        int s = tid + i * 256;
        vals[i] = psc[b * SS + s];
        msk[i]  = mask[b * SS + s];
        if (!msk[i]) lmax = fmaxf(lmax, vals[i]);
    }
    sred[tid] = lmax; __syncthreads();
    for (int off = 128; off > 0; off >>= 1) {
        if (tid < off) sred[tid] = fmaxf(sred[tid], sred[tid + off]);
        __syncthreads();
    }
    float m = sred[0];
    __syncthreads();
    float ex[8];
    float lsum = 0.f;
    #pragma unroll
    for (int i = 0; i < 8; i++) {
        ex[i] = msk[i] ? 0.f : __expf(vals[i] - m);
        lsum += ex[i];
    }
    sred[tid] = lsum; __syncthreads();
    for (int off = 128; off > 0; off >>= 1) {
        if (tid < off) sred[tid] += sred[tid + off];
        __syncthreads();
    }
    float inv = 1.f / sred[0];
    #pragma unroll
    for (int i = 0; i < 8; i++) attn[b * SS + tid + i * 256] = ex[i] * inv;
}

// ---------------- ctx partials over s-chunks, masked-skip (no atomics) ----------
__global__ __launch_bounds__(256) void k_ctx_part(const float* __restrict__ enc,
                                                  const float* __restrict__ attn,
                                                  float* __restrict__ pctx) {
    const int b = blockIdx.x, z = blockIdx.y, tid = threadIdx.x;   // z: 0..31, 64 rows each
    float4 acc = {0.f, 0.f, 0.f, 0.f};
    const float4* e4 = (const float4*)(enc + ((size_t)b * SS + z * 64) * HE);
    const float*  ar = attn + b * SS + z * 64;
    for (int s = 0; s < 64; s++) {
        float a = ar[s];
        if (a != 0.f) {   // masked tokens have exactly-zero attn -> skip row read
            float4 v = e4[(size_t)s * 256 + tid];
            acc.x += a * v.x; acc.y += a * v.y; acc.z += a * v.z; acc.w += a * v.w;
        }
    }
    *(float4*)(pctx + ((size_t)z * 32 + b) * 1024 + tid * 4) = acc;
}

__global__ __launch_bounds__(256) void k_ctx_red(const float* __restrict__ pctx,
                                                 float* __restrict__ ctx) {
    int i = blockIdx.x * 256 + threadIdx.x;   // 0..32767
    float s = 0.f;
    #pragma unroll
    for (int z = 0; z < 32; z++) s += pctx[z * 32768 + i];
    ctx[i] = s;
}

// ================= fp32 fallback (round-0 proven path) =================
__global__ __launch_bounds__(256) void k_scores_f32(const float* __restrict__ enc,
                                                    const float* __restrict__ W,
                                                    const float* __restrict__ V,
                                                    const float* __restrict__ proj,
                                                    float* __restrict__ scores) {
    __shared__ float As[64][20];
    __shared__ float Bs[64][20];
    __shared__ float red[64][17];
    const int t0 = blockIdx.x * 64;
    const int b  = t0 >> 11;
    const int tid = threadIdx.x;
    const int tx = tid & 15, ty = tid >> 4;
    const int lrow = tid >> 2, lc4 = (tid & 3) * 4;
    float sc[4] = {0.f, 0.f, 0.f, 0.f};
    for (int n0 = 0; n0 < HD; n0 += 64) {
        float C[4][4] = {};
        for (int k0 = 0; k0 < HE; k0 += 16) {
            *(float4*)&As[lrow][lc4] = *(const float4*)(enc + (size_t)(t0 + lrow) * HE + k0 + lc4);
            *(float4*)&Bs[lrow][lc4] = *(const float4*)(W + (size_t)(n0 + lrow) * WROW + k0 + lc4);
            __syncthreads();
            #pragma unroll
            for (int k4 = 0; k4 < 16; k4 += 4) {
                float4 a[4], bb[4];
                #pragma unroll
                for (int i = 0; i < 4; i++) a[i]  = *(float4*)&As[ty * 4 + i][k4];
                #pragma unroll
                for (int j = 0; j < 4; j++) bb[j] = *(float4*)&Bs[tx * 4 + j][k4];
                #pragma unroll
                for (int i = 0; i < 4; i++)
                    #pragma unroll
                    for (int j = 0; j < 4; j++)
                        C[i][j] += a[i].x * bb[j].x + a[i].y * bb[j].y +
                                   a[i].z * bb[j].z + a[i].w * bb[j].w;
            }
            __syncthreads();
        }
        #pragma unroll
        for (int j = 0; j < 4; j++) {
            int d = n0 + tx * 4 + j;
            float pd = proj[b * HD + d];
            float v  = V[d];
            #pragma unroll
            for (int i = 0; i < 4; i++) {
                float y  = C[i][j] + pd;
                float e2 = __expf(2.f * y);
                sc[i] += v * (1.f - 2.f / (e2 + 1.f));
            }
        }
    }
    #pragma unroll
    for (int i = 0; i < 4; i++) red[ty * 4 + i][tx] = sc[i];
    __syncthreads();
    if (tid < 64) {
        float s = 0.f;
        #pragma unroll
        for (int x = 0; x < 16; x++) s += red[tid][x];
        scores[t0 + tid] = s;
    }
}

__global__ __launch_bounds__(256) void k_softmax_f32(float* __restrict__ sc_attn,
                                                     const int* __restrict__ mask) {
    __shared__ float sred[256];
    const int b = blockIdx.x, tid = threadIdx.x;
    float vals[8]; int msk[8];
    float lmax = -1e30f;
    #pragma unroll
    for (int i = 0; i < 8; i++) {
        int s = tid + i * 256;
        vals[i] = sc_attn[b * SS + s];
        msk[i]  = mask[b * SS + s];
        if (!msk[i]) lmax = fmaxf(lmax, vals[i]);
    }
    sred[tid] = lmax; __syncthreads();
    for (int off = 128; off > 0; off >>= 1) {
        if (tid < off) sred[tid] = fmaxf(sred[tid], sred[tid + off]);
        __syncthreads();
    }
    float m = sred[0];
    __syncthreads();
    float ex[8]; float lsum = 0.f;
    #pragma unroll
    for (int i = 0; i < 8; i++) { ex[i] = msk[i] ? 0.f : __expf(vals[i] - m); lsum += ex[i]; }
    sred[tid] = lsum; __syncthreads();
    for (int off = 128; off > 0; off >>= 1) {
        if (tid < off) sred[tid] += sred[tid + off];
        __syncthreads();
    }
    float inv = 1.f / sred[0];
    #pragma unroll
    for (int i = 0; i < 8; i++) sc_attn[b * SS + tid + i * 256] = ex[i] * inv;
}

__global__ __launch_bounds__(256) void k_ctx_atomic(const float* __restrict__ enc,
                                                    const float* __restrict__ attn,
                                                    float* __restrict__ ctx) {
    const int b = blockIdx.x;
    const int e = blockIdx.y * 256 + threadIdx.x;
    const int s0 = blockIdx.z * 256;
    float sum = 0.f;
    for (int s = s0; s < s0 + 256; s++)
        sum += attn[b * SS + s] * enc[((size_t)b * SS + s) * HE + e];
    atomicAdd(&ctx[b * HE + e], sum);
}

extern "C" void kernel_launch(void* const* d_in, const int* in_sizes, int n_in,
                              void* d_out, int out_size, void* d_ws, size_t ws_size,
                              hipStream_t stream) {
    const float* enc  = (const float*)d_in[0];
    const float* dec  = (const float*)d_in[1];
    const int*   mask = (const int*)d_in[2];
    const float* W    = (const float*)d_in[3];
    const float* V    = (const float*)d_in[4];

    float* out  = (float*)d_out;
    float* ctx  = out;               // [32][1024]
    float* attn = out + BB * HE;     // [32][2048]

    // ws layout (bytes): wf 2 MiB | proj 128 KiB | psc 1 MiB | pctx 4 MiB
    const size_t WF_OFF = 0, PROJ_OFF = 2097152, PSC_OFF = PROJ_OFF + 131072,
                 PCTX_OFF = PSC_OFF + 1048576, WS_NEED = PCTX_OFF + 4194304;
    if (ws_size >= WS_NEED) {
        char* w = (char*)d_ws;
        unsigned short* wf = (unsigned short*)(w + WF_OFF);
        float* proj        = (float*)(w + PROJ_OFF);
        float* psc         = (float*)(w + PSC_OFF);
        float* pctx        = (float*)(w + PCTX_OFF);

        k_cvt_wfrag<<<512, 256, 0, stream>>>(W, wf);
        k_projdec2<<<256, 256, 0, stream>>>(dec, W, proj);
        k_scores_mfma8b<<<1024, 512, 0, stream>>>(enc, wf, V, proj, psc);
        k_softmax_p<<<BB, 256, 0, stream>>>(psc, mask, attn);
        k_ctx_part<<<dim3(BB, 32), 256, 0, stream>>>(enc, attn, pctx);
        k_ctx_red<<<128, 256, 0, stream>>>(pctx, ctx);
    } else {
        float* proj  = ctx;
        float* score = attn;
        k_projdec2<<<256, 256, 0, stream>>>(dec, W, proj);
        k_scores_f32<<<(BB * SS) / 64, 256, 0, stream>>>(enc, W, V, proj, score);
        k_softmax_f32<<<BB, 256, 0, stream>>>(score, mask);
        hipMemsetAsync(ctx, 0, (size_t)BB * HE * sizeof(float), stream);
        k_ctx_atomic<<<dim3(BB, HE / 256, 8), 256, 0, stream>>>(enc, attn, ctx);
    }
}

// Round 6
// 187.449 us; speedup vs baseline: 1.5653x; 1.1831x over previous
//
#include <hip/hip_runtime.h>
#include <hip/hip_bf16.h>
#include <math.h>

#define BB 32
#define SS 2048
#define HE 1024
#define HD 1024
#define WROW (HE + HD)   // 2048

typedef __attribute__((ext_vector_type(8))) short bf16x8;
typedef __attribute__((ext_vector_type(4))) float f32x4;
typedef __attribute__((ext_vector_type(16))) float f32x16;
typedef __attribute__((ext_vector_type(8))) unsigned short u16x8;

__device__ __forceinline__ unsigned short f2bf(float f) {
    union { float f; unsigned u; } v; v.f = f;
    unsigned r = v.u + 0x7fffu + ((v.u >> 16) & 1u);   // RNE
    return (unsigned short)(r >> 16);
}

__device__ __forceinline__ unsigned int pk2(float x, float y) {
    union { __hip_bfloat162 h; unsigned int u; } c;
    c.h = __float22bfloat162_rn(float2{x, y});          // v_cvt_pk_bf16_f32
    return c.u;
}

#define LGKM0()  asm volatile("s_waitcnt lgkmcnt(0)" ::: "memory")
#define BAR()    asm volatile("s_barrier" ::: "memory")

// ---------------- cvt: W_enc fp32 -> bf16 fragment-major (32x32x16 records) ----
// Record (g, ks): 64 lanes x 16B; lane l = W[d=g*32+(l&31)][k=ks*16+(l>>5)*8 ..+8]
__global__ __launch_bounds__(256) void k_cvt_wfrag(const float* __restrict__ W,
                                                   unsigned short* __restrict__ wf) {
    int i = blockIdx.x * 256 + threadIdx.x;   // 0..131071 (8-elem chunks)
    int d = i >> 7;                            // 0..1023
    int c = i & 127;                           // k-chunk: k = c*8
    const float4* src = (const float4*)(W + (size_t)d * WROW + c * 8);
    float4 a = src[0], b2 = src[1];
    u16x8 o;
    o[0] = f2bf(a.x);  o[1] = f2bf(a.y);  o[2] = f2bf(a.z);  o[3] = f2bf(a.w);
    o[4] = f2bf(b2.x); o[5] = f2bf(b2.y); o[6] = f2bf(b2.z); o[7] = f2bf(b2.w);
    int ks = c >> 1;                           // k>>4
    int l  = (d & 31) + 32 * (c & 1);          // (l>>5) = k-half
    int g  = d >> 5;
    *(u16x8*)(wf + ((size_t)(g * 64 + ks) * 64 + l) * 8) = o;
}

// ---------------- proj_dec: W_dec read ONCE total ----------------
__global__ __launch_bounds__(256) void k_projdec2(const float* __restrict__ dec,
                                                  const float* __restrict__ W,
                                                  float* __restrict__ proj) {
    const int tid = threadIdx.x;
    const int dl = tid >> 6;
    const int b  = (tid >> 1) & 31;
    const int hf = tid & 1;
    const int d  = blockIdx.x * 4 + dl;
    const float* wrow = W + (size_t)d * WROW + HE + hf * 512;
    const float* dv   = dec + b * HD + hf * 512;
    float s = 0.f;
    #pragma unroll 4
    for (int e = 0; e < 512; e += 4) {
        float4 w4 = *(const float4*)(wrow + e);
        float4 x4 = *(const float4*)(dv + e);
        s += w4.x * x4.x + w4.y * x4.y + w4.z * x4.z + w4.w * x4.w;
    }
    s += __shfl_xor(s, 1, 64);
    if (hf == 0) proj[b * HD + d] = s;
}

// ---------------- mask compaction: per-batch list of UNMASKED tokens ----------
// ~50% of tokens are masked (attn exactly 0, scores never observed) -> the
// scores GEMM only needs unmasked rows. Wave-ballot compaction, pad to 64
// with sentinel (bit31 set -> compute on row 0, skip store).
__global__ __launch_bounds__(64) void k_compact(const int* __restrict__ mask,
                                                int* __restrict__ idx,
                                                int* __restrict__ cntblk) {
    const int b = blockIdx.x, ln = threadIdx.x;   // 32 blocks x 64 lanes
    int running = 0;
    for (int s0 = 0; s0 < SS; s0 += 64) {
        int m = mask[b * SS + s0 + ln];
        unsigned long long bal = __ballot(m == 0);
        int pos = __popcll(bal & ((1ull << ln) - 1ull));
        if (m == 0) idx[b * SS + running + pos] = s0 + ln;
        running += __popcll(bal);
    }
    int padded = (running + 63) & ~63;
    for (int i = running + ln; i < padded; i += 64) idx[b * SS + i] = (int)0x80000000;
    if (ln == 0) cntblk[b] = padded >> 6;
}

// blocktab[j] = (b<<16)|local_block for global compact block j, else -1
__global__ __launch_bounds__(1024) void k_blocktab(const int* __restrict__ cntblk,
                                                   int* __restrict__ btab) {
    __shared__ int off[33];
    if (threadIdx.x == 0) {
        int a = 0;
        for (int i = 0; i < 32; i++) { off[i] = a; a += cntblk[i]; }
        off[32] = a;
    }
    __syncthreads();
    int j = threadIdx.x, e = -1;
    #pragma unroll
    for (int b2 = 0; b2 < 32; b2++)
        if (j >= off[b2] && j < off[b2 + 1]) e = (b2 << 16) | (j - off[b2]);
    btab[j] = e;
}

// ---------------- 8-wave 64x1024 scores, 32x32x16 MFMA, COMPACTED rows -------
// R6: R5 core (64 tokens x full d, A staged once, 8 waves x 64x128, single
// lgkm0+barrier per K-tile) on the compacted token list: block handles 64
// unmasked tokens of one batch via idx[] gather (row-granular, free: each
// thread's A-row is K-invariant, one index load per thread). Dead blocks
// early-exit. ~50% of the GEMM work eliminated.
__global__ __launch_bounds__(512, 2) void k_scores_mfma8b(
        const float* __restrict__ enc,             // [65536][1024] fp32
        const unsigned short* __restrict__ wf,     // fragment-major bf16 W_enc
        const float* __restrict__ V,
        const float* __restrict__ proj,            // [32][1024]
        const int* __restrict__ idx,               // [32][2048] compacted tokens
        const int* __restrict__ btab,              // [1024] block table
        float* __restrict__ psc) {                 // [65536] scores (b*SS+s)
    __shared__ unsigned short SM[8192];            // 16 KB: A dbuf [2][4096]

    const int ent = btab[blockIdx.x];
    if (ent < 0) return;

    const int tid = threadIdx.x;
    const int wv = tid >> 6, ln = tid & 63, l31 = ln & 31, hi = ln >> 5;
    const int b   = ent >> 16;
    const int lt0 = (ent & 0xffff) << 6;           // local compact token base

    // per-thread A row (K-invariant): gather via compact index
    const int rid = idx[b * SS + lt0 + (tid >> 3)];
    const size_t arow = ((size_t)b * SS + (rid & 0xffff)) * 1024;

    f32x16 acc[2][4];
    #pragma unroll
    for (int m = 0; m < 2; m++)
        #pragma unroll
        for (int n = 0; n < 4; n++)
            #pragma unroll
            for (int r = 0; r < 16; r++) acc[m][n][r] = 0.f;

    float4 areg[2];            // one K-tile of A: 64 rows x 64 k fp32, 8 fp32/thread
    bf16x8 bgE[8], bgF[8];     // B frags: [kk*4+n], E = ks 0,1  F = ks 2,3

    #define LOAD_A(k) do { \
        const float4* g_ = (const float4*)(enc + arow + (k) + (tid & 7) * 8); \
        areg[0] = g_[0]; areg[1] = g_[1]; \
    } while (0)

    #define CVTW_A(buf) do { \
        int row_ = tid >> 3; \
        union { u16x8 s; uint4 u; } pk_; \
        pk_.u.x = pk2(areg[0].x, areg[0].y); \
        pk_.u.y = pk2(areg[0].z, areg[0].w); \
        pk_.u.z = pk2(areg[1].x, areg[1].y); \
        pk_.u.w = pk2(areg[1].z, areg[1].w); \
        *(u16x8*)&SM[(buf) * 4096 + row_ * 64 + (((tid & 7) ^ (row_ & 7)) << 3)] = pk_.s; \
    } while (0)

    // B record: (g = wv*4 + n)*64 + t*4 + ksabs, lane ln
    #define LOADB(bgx, tt, ksb) do { \
        _Pragma("unroll") \
        for (int kk = 0; kk < 2; kk++) \
            _Pragma("unroll") \
            for (int n = 0; n < 4; n++) \
                bgx[kk * 4 + n] = *(const bf16x8*)(wf + ((size_t)((wv * 4 + n) * 64 + (tt) * 4 + (ksb) + kk) * 64 + ln) * 8); \
        } while (0)

    // one half-K-step (2 ks) of the wave-tile: 4 ds_reads + 16 MFMA
    #define HALF(bg, ksb, Ac) do { \
        _Pragma("unroll") \
        for (int kk = 0; kk < 2; kk++) { \
            bf16x8 af0, af1; \
            { int c_ = ((ksb) + kk) * 2 + hi; int row_ = l31; \
              af0 = *(const bf16x8*)&(Ac)[row_ * 64 + ((c_ ^ (row_ & 7)) << 3)]; } \
            { int c_ = ((ksb) + kk) * 2 + hi; int row_ = 32 + l31; \
              af1 = *(const bf16x8*)&(Ac)[row_ * 64 + ((c_ ^ (row_ & 7)) << 3)]; } \
            __builtin_amdgcn_s_setprio(1); \
            _Pragma("unroll") \
            for (int n = 0; n < 4; n++) \
                acc[0][n] = __builtin_amdgcn_mfma_f32_32x32x16_bf16(af0, bg[kk * 4 + n], acc[0][n], 0, 0, 0); \
            _Pragma("unroll") \
            for (int n = 0; n < 4; n++) \
                acc[1][n] = __builtin_amdgcn_mfma_f32_32x32x16_bf16(af1, bg[kk * 4 + n], acc[1][n], 0, 0, 0); \
            __builtin_amdgcn_s_setprio(0); \
        } } while (0)

    // ---- prologue: bg(0) both halves, A(0)->LDS, A(1) in flight ----
    LOADB(bgE, 0, 0); LOADB(bgF, 0, 2);
    LOAD_A(0);
    CVTW_A(0);                 // compiler waits A(0) loads, leaves bg in flight
    LOAD_A(64);                // A(1)
    LGKM0(); BAR();

    for (int t = 0; t < 16; ++t) {
        const int cur = t & 1, nxt = cur ^ 1;
        const unsigned short* Ac = SM + cur * 4096;

        // ks 0,1
        HALF(bgE, 0, Ac);

        // slot: bgE dead -> reload for t+1; convert A(t+1)->LDS nxt; issue A(t+2)
        if (t < 15) {
            LOADB(bgE, t + 1, 0);
            CVTW_A(nxt);                       // counted vmcnt on areg only
            if (t < 14) LOAD_A((t + 2) * 64);
        }

        // ks 2,3
        HALF(bgF, 2, Ac);

        if (t < 15) {
            LOADB(bgF, t + 1, 2);
            LGKM0(); BAR();                    // A dbuf coherence; B stays in flight
        }
    }
    #undef LOAD_A
    #undef CVTW_A
    #undef LOADB
    #undef HALF

    // ---- fused epilogue: sc[m][r] = sum_n V[d]*tanh(acc + proj) ----
    float sc[2][16];
    #pragma unroll
    for (int m = 0; m < 2; m++)
        #pragma unroll
        for (int r = 0; r < 16; r++) sc[m][r] = 0.f;
    #pragma unroll
    for (int n = 0; n < 4; n++) {
        int d = wv * 128 + n * 32 + l31;
        float pd  = proj[b * 1024 + d];
        float vv  = V[d];
        float vv2 = 2.f * vv;
        #pragma unroll
        for (int m = 0; m < 2; m++)
            #pragma unroll
            for (int r = 0; r < 16; r++) {
                float y  = acc[m][n][r] + pd;
                float e2 = __expf(2.f * y);                 // saturates at +/-inf
                float rc = __builtin_amdgcn_rcpf(e2 + 1.f);
                sc[m][r] += vv - vv2 * rc;                  // vv * tanh(y)
            }
    }

    // butterfly sum over the 32-lane column group (halves independent)
    #pragma unroll
    for (int m = 0; m < 2; m++)
        #pragma unroll
        for (int r = 0; r < 16; r++) {
            float v = sc[m][r];
            v += __shfl_xor(v, 1, 64);
            v += __shfl_xor(v, 2, 64);
            v += __shfl_xor(v, 4, 64);
            v += __shfl_xor(v, 8, 64);
            v += __shfl_xor(v, 16, 64);
            sc[m][r] = v;
        }

    __syncthreads();           // all waves done with LDS; safe to alias
    float* redf = (float*)SM;  // [64 tokens][8 waves] f32 = 2KB
    if (l31 == 0) {
        #pragma unroll
        for (int m = 0; m < 2; m++)
            #pragma unroll
            for (int r = 0; r < 16; r++) {
                int tok = m * 32 + (r & 3) + 8 * (r >> 2) + 4 * hi;
                redf[tok * 8 + wv] = sc[m][r];
            }
    }
    __syncthreads();
    if (tid < 64) {
        float s = 0.f;
        #pragma unroll
        for (int w = 0; w < 8; w++) s += redf[tid * 8 + w];
        int sidx = idx[b * SS + lt0 + tid];
        if (sidx >= 0) psc[b * SS + sidx] = s;   // skip sentinel pads
    }
}

// ---------------- masked softmax over S ----------------
// psc entries for masked tokens are garbage (never written) but are provably
// never read into the result: masked lanes contribute neither to max nor sum.
__global__ __launch_bounds__(256) void k_softmax_p(const float* __restrict__ psc,
                                                   const int* __restrict__ mask,
                                                   float* __restrict__ attn) {
    __shared__ float sred[256];
    const int b = blockIdx.x, tid = threadIdx.x;
    float vals[8];
    int   msk[8];
    float lmax = -1e30f;
    #pragma unroll
    for (int i = 0; i < 8; i++) {
        int s = tid + i * 256;
        msk[i]  = mask[b * SS + s];
        vals[i] = msk[i] ? 0.f : psc[b * SS + s];
        if (!msk[i]) lmax = fmaxf(lmax, vals[i]);
    }
    sred[tid] = lmax; __syncthreads();
    for (int off = 128; off > 0; off >>= 1) {
        if (tid < off) sred[tid] = fmaxf(sred[tid], sred[tid + off]);
        __syncthreads();
    }
    float m = sred[0];
    __syncthreads();
    float ex[8];
    float lsum = 0.f;
    #pragma unroll
    for (int i = 0; i < 8; i++) {
        ex[i] = msk[i] ? 0.f : __expf(vals[i] - m);
        lsum += ex[i];
    }
    sred[tid] = lsum; __syncthreads();
    for (int off = 128; off > 0; off >>= 1) {
        if (tid < off) sred[tid] += sred[tid + off];
        __syncthreads();
    }
    float inv = 1.f / sred[0];
    #pragma unroll
    for (int i = 0; i < 8; i++) attn[b * SS + tid + i * 256] = ex[i] * inv;
}

// ---------------- ctx partials over s-chunks, masked-skip (no atomics) ----------
__global__ __launch_bounds__(256) void k_ctx_part(const float* __restrict__ enc,
                                                  const float* __restrict__ attn,
                                                  float* __restrict__ pctx) {
    const int b = blockIdx.x, z = blockIdx.y, tid = threadIdx.x;   // z: 0..31, 64 rows each
    float4 acc = {0.f, 0.f, 0.f, 0.f};
    const float4* e4 = (const float4*)(enc + ((size_t)b * SS + z * 64) * HE);
    const float*  ar = attn + b * SS + z * 64;
    for (int s = 0; s < 64; s++) {
        float a = ar[s];
        if (a != 0.f) {   // masked tokens have exactly-zero attn -> skip row read
            float4 v = e4[(size_t)s * 256 + tid];
            acc.x += a * v.x; acc.y += a * v.y; acc.z += a * v.z; acc.w += a * v.w;
        }
    }
    *(float4*)(pctx + ((size_t)z * 32 + b) * 1024 + tid * 4) = acc;
}

__global__ __launch_bounds__(256) void k_ctx_red(const float* __restrict__ pctx,
                                                 float* __restrict__ ctx) {
    int i = blockIdx.x * 256 + threadIdx.x;   // 0..32767
    float s = 0.f;
    #pragma unroll
    for (int z = 0; z < 32; z++) s += pctx[z * 32768 + i];
    ctx[i] = s;
}

// ================= fp32 fallback (round-0 proven path) =================
__global__ __launch_bounds__(256) void k_scores_f32(const float* __restrict__ enc,
                                                    const float* __restrict__ W,
                                                    const float* __restrict__ V,
                                                    const float* __restrict__ proj,
                                                    float* __restrict__ scores) {
    __shared__ float As[64][20];
    __shared__ float Bs[64][20];
    __shared__ float red[64][17];
    const int t0 = blockIdx.x * 64;
    const int b  = t0 >> 11;
    const int tid = threadIdx.x;
    const int tx = tid & 15, ty = tid >> 4;
    const int lrow = tid >> 2, lc4 = (tid & 3) * 4;
    float sc[4] = {0.f, 0.f, 0.f, 0.f};
    for (int n0 = 0; n0 < HD; n0 += 64) {
        float C[4][4] = {};
        for (int k0 = 0; k0 < HE; k0 += 16) {
            *(float4*)&As[lrow][lc4] = *(const float4*)(enc + (size_t)(t0 + lrow) * HE + k0 + lc4);
            *(float4*)&Bs[lrow][lc4] = *(const float4*)(W + (size_t)(n0 + lrow) * WROW + k0 + lc4);
            __syncthreads();
            #pragma unroll
            for (int k4 = 0; k4 < 16; k4 += 4) {
                float4 a[4], bb[4];
                #pragma unroll
                for (int i = 0; i < 4; i++) a[i]  = *(float4*)&As[ty * 4 + i][k4];
                #pragma unroll
                for (int j = 0; j < 4; j++) bb[j] = *(float4*)&Bs[tx * 4 + j][k4];
                #pragma unroll
                for (int i = 0; i < 4; i++)
                    #pragma unroll
                    for (int j = 0; j < 4; j++)
                        C[i][j] += a[i].x * bb[j].x + a[i].y * bb[j].y +
                                   a[i].z * bb[j].z + a[i].w * bb[j].w;
            }
            __syncthreads();
        }
        #pragma unroll
        for (int j = 0; j < 4; j++) {
            int d = n0 + tx * 4 + j;
            float pd = proj[b * HD + d];
            float v  = V[d];
            #pragma unroll
            for (int i = 0; i < 4; i++) {
                float y  = C[i][j] + pd;
                float e2 = __expf(2.f * y);
                sc[i] += v * (1.f - 2.f / (e2 + 1.f));
            }
        }
    }
    #pragma unroll
    for (int i = 0; i < 4; i++) red[ty * 4 + i][tx] = sc[i];
    __syncthreads();
    if (tid < 64) {
        float s = 0.f;
        #pragma unroll
        for (int x = 0; x < 16; x++) s += red[tid][x];
        scores[t0 + tid] = s;
    }
}

__global__ __launch_bounds__(256) void k_softmax_f32(float* __restrict__ sc_attn,
                                                     const int* __restrict__ mask) {
    __shared__ float sred[256];
    const int b = blockIdx.x, tid = threadIdx.x;
    float vals[8]; int msk[8];
    float lmax = -1e30f;
    #pragma unroll
    for (int i = 0; i < 8; i++) {
        int s = tid + i * 256;
        vals[i] = sc_attn[b * SS + s];
        msk[i]  = mask[b * SS + s];
        if (!msk[i]) lmax = fmaxf(lmax, vals[i]);
    }
    sred[tid] = lmax; __syncthreads();
    for (int off = 128; off > 0; off >>= 1) {
        if (tid < off) sred[tid] = fmaxf(sred[tid], sred[tid + off]);
        __syncthreads();
    }
    float m = sred[0];
    __syncthreads();
    float ex[8]; float lsum = 0.f;
    #pragma unroll
    for (int i = 0; i < 8; i++) { ex[i] = msk[i] ? 0.f : __expf(vals[i] - m); lsum += ex[i]; }
    sred[tid] = lsum; __syncthreads();
    for (int off = 128; off > 0; off >>= 1) {
        if (tid < off) sred[tid] += sred[tid + off];
        __syncthreads();
    }
    float inv = 1.f / sred[0];
    #pragma unroll
    for (int i = 0; i < 8; i++) sc_attn[b * SS + tid + i * 256] = ex[i] * inv;
}

__global__ __launch_bounds__(256) void k_ctx_atomic(const float* __restrict__ enc,
                                                    const float* __restrict__ attn,
                                                    float* __restrict__ ctx) {
    const int b = blockIdx.x;
    const int e = blockIdx.y * 256 + threadIdx.x;
    const int s0 = blockIdx.z * 256;
    float sum = 0.f;
    for (int s = s0; s < s0 + 256; s++)
        sum += attn[b * SS + s] * enc[((size_t)b * SS + s) * HE + e];
    atomicAdd(&ctx[b * HE + e], sum);
}

extern "C" void kernel_launch(void* const* d_in, const int* in_sizes, int n_in,
                              void* d_out, int out_size, void* d_ws, size_t ws_size,
                              hipStream_t stream) {
    const float* enc  = (const float*)d_in[0];
    const float* dec  = (const float*)d_in[1];
    const int*   mask = (const int*)d_in[2];
    const float* W    = (const float*)d_in[3];
    const float* V    = (const float*)d_in[4];

    float* out  = (float*)d_out;
    float* ctx  = out;               // [32][1024]
    float* attn = out + BB * HE;     // [32][2048]

    // ws layout (bytes): wf 2M | proj 128K | psc 256K | pctx 4M | idx 256K | cnt 4K | btab 4K
    const size_t WF_OFF = 0, PROJ_OFF = 2097152, PSC_OFF = PROJ_OFF + 131072,
                 PCTX_OFF = PSC_OFF + 262144, IDX_OFF = PCTX_OFF + 4194304,
                 CNT_OFF = IDX_OFF + 262144, BT_OFF = CNT_OFF + 4096,
                 WS_NEED = BT_OFF + 4096;
    if (ws_size >= WS_NEED) {
        char* w = (char*)d_ws;
        unsigned short* wf = (unsigned short*)(w + WF_OFF);
        float* proj        = (float*)(w + PROJ_OFF);
        float* psc         = (float*)(w + PSC_OFF);
        float* pctx        = (float*)(w + PCTX_OFF);
        int*   idx         = (int*)(w + IDX_OFF);
        int*   cntblk      = (int*)(w + CNT_OFF);
        int*   btab        = (int*)(w + BT_OFF);

        k_compact<<<BB, 64, 0, stream>>>(mask, idx, cntblk);
        k_blocktab<<<1, 1024, 0, stream>>>(cntblk, btab);
        k_cvt_wfrag<<<512, 256, 0, stream>>>(W, wf);
        k_projdec2<<<256, 256, 0, stream>>>(dec, W, proj);
        k_scores_mfma8b<<<1024, 512, 0, stream>>>(enc, wf, V, proj, idx, btab, psc);
        k_softmax_p<<<BB, 256, 0, stream>>>(psc, mask, attn);
        k_ctx_part<<<dim3(BB, 32), 256, 0, stream>>>(enc, attn, pctx);
        k_ctx_red<<<128, 256, 0, stream>>>(pctx, ctx);
    } else {
        float* proj  = ctx;
        float* score = attn;
        k_projdec2<<<256, 256, 0, stream>>>(dec, W, proj);
        k_scores_f32<<<(BB * SS) / 64, 256, 0, stream>>>(enc, W, V, proj, score);
        k_softmax_f32<<<BB, 256, 0, stream>>>(score, mask);
        hipMemsetAsync(ctx, 0, (size_t)BB * HE * sizeof(float), stream);
        k_ctx_atomic<<<dim3(BB, HE / 256, 8), 256, 0, stream>>>(enc, attn, ctx);
    }
}